// Round 5
// baseline (703.145 us; speedup 1.0000x reference)
//
#include <hip/hip_runtime.h>
#include <cstdint>
#include <cstddef>

#define BSZ 16
#define TLEN 2048
#define CDIM 1024
#define OUTDIM 512
#define MAXF 512

typedef _Float16 f16x8 __attribute__((ext_vector_type(8)));
typedef _Float16 f16x4 __attribute__((ext_vector_type(4)));
typedef float f32x16 __attribute__((ext_vector_type(16)));

__device__ __forceinline__ void gl_lds16(const void* g, void* l) {
    __builtin_amdgcn_global_load_lds(
        (const __attribute__((address_space(1))) void*)g,
        (__attribute__((address_space(3))) void*)l, 16, 0, 0);
}

// exact 2-term fp16 split: a = h0 + h1 * 2^-11  (h1 pre-scaled by 2^11)
struct h2pair { _Float16 h0, h1; };
__device__ __forceinline__ h2pair split2(float a) {
    h2pair o;
    o.h0 = (_Float16)a;
    float r = a - (float)o.h0;       // exact (Sterbenz)
    o.h1 = (_Float16)(r * 2048.0f);
    return o;
}

// ============================================================================
// k0a: split Wd into 2 fp16 planes in k1's TILED layout:
// plane[(dut*32+ktl)*4096 + (c*128 + r)*8 + j] = Wd[dut*128+r][ktl*32+c*8+j]
// ============================================================================
__global__ __launch_bounds__(128) void k0a_split_wd(
    const float* __restrict__ Wd, _Float16* __restrict__ B0,
    _Float16* __restrict__ B1)
{
    const int dut = blockIdx.x;     // 8
    const int ktl = blockIdx.y;     // 32
    const int r = threadIdx.x;      // 128
    const float* src = Wd + (size_t)(dut * 128 + r) * CDIM + ktl * 32;
    float v[32];
#pragma unroll
    for (int j = 0; j < 8; j++) *(float4*)&v[j * 4] = *(const float4*)(src + j * 4);
    const size_t tb = (size_t)(dut * 32 + ktl) * 4096;
#pragma unroll
    for (int c = 0; c < 4; c++) {
        f16x8 h0, h1;
#pragma unroll
        for (int j = 0; j < 8; j++) {
            h2pair s = split2(v[c * 8 + j]);
            h0[j] = s.h0;
            h1[j] = s.h1;
        }
        *(f16x8*)&B0[tb + (c * 128 + r) * 8] = h0;
        *(f16x8*)&B1[tb + (c * 128 + r) * 8] = h1;
    }
}

// ============================================================================
// k0c: split Wo into 2 fp16 planes, row-major [o][k]
// ============================================================================
__global__ __launch_bounds__(256) void k0c_split_wo(
    const float* __restrict__ Wo, _Float16* __restrict__ W0,
    _Float16* __restrict__ W1)
{
    const int i = (blockIdx.x * 256 + threadIdx.x) * 4;
    float4 v = *(const float4*)(Wo + i);
    f16x4 h0, h1;
    h2pair s0 = split2(v.x); h0[0] = s0.h0; h1[0] = s0.h1;
    h2pair s1 = split2(v.y); h0[1] = s1.h0; h1[1] = s1.h1;
    h2pair s2 = split2(v.z); h0[2] = s2.h0; h1[2] = s2.h1;
    h2pair s3 = split2(v.w); h0[3] = s3.h0; h1[3] = s3.h1;
    *(f16x4*)&W0[i] = h0;
    *(f16x4*)&W1[i] = h1;
}

// ============================================================================
// k1: g[row] = sum_du Wp[du]*relu(enc[row,:].Wd[du,:] + bd[du])
// fp16 2-term split, 3 MFMA products, accumulation order bit-identical to
// prior round. BM=BN=128, BK=32; 1024 threads = 16 waves (4M x 4N), wave
// tile 32x32 -> acc+accc = 32 AGPR. A staged by in-kernel split into LDS
// (4 floats/thread, conflict-free tiled layout); B (Wd planes, L2-resident
// per R3's FETCH evidence) loaded DIRECT to registers, double-buffered --
// zero B LDS traffic. Per-CU LDS demand at full MFMA rate: 52 B/cy vs 85
// ceiling (38% slack; R4 was 124 -> saturated). B/fa are register loads so
// the compiler inserts exact counted vmcnt waits itself; fences only pin
// issue order. One barrier per K-step, lgkm-drained.
// ============================================================================
__global__ __launch_bounds__(1024, 4) void k1_weight_gemm(
    const float* __restrict__ enc, const _Float16* __restrict__ BT0,
    const _Float16* __restrict__ BT1, const float* __restrict__ bd,
    const float* __restrict__ Wp, float* __restrict__ g)
{
    // 2 buffers x (A0 | A1 planes of 4096 halves) = 16384 halves = 32 KB
    __shared__ __align__(16) _Float16 lds[16384];

    const int tid = threadIdx.x;
    const int lane = tid & 63;
    const int wv = tid >> 6;        // 0..15
    const int l5 = lane & 31;
    const int hi = lane >> 5;
    const int wm = wv & 3;          // M quarter (32 rows)
    const int wn = wv >> 2;         // N quarter (32 du)

    // XCD-aware decode: xcd = bx%8; each xcd handles 32 row-groups x 8 du
    const int bx = blockIdx.x;
    const int xcd = bx & 7;
    const int j = bx >> 3;
    const int rg = xcd * 32 + (j >> 3);
    const int dug = j & 7;
    const long row0 = (long)rg * 128;
    const int du0 = dug * 128;

    // A staging: thread -> (sr = row, sq = k-quad), 4 floats each
    const int sr = tid >> 3;        // 0..127
    const int sq = tid & 7;         // 0..7
    const float* aptr = enc + (row0 + sr) * (long)CDIM + sq * 4;
    const int awofs = ((sq >> 1) * 128 + sr) * 8 + (sq & 1) * 4;

    // B: per-lane pointers into tiled Wd planes (frag (kt,ch) at +kt*4096+ch*2048)
    const _Float16* bt0 = BT0 + (size_t)(dug * 32) * 4096
                        + (size_t)(hi * 128 + wn * 32 + l5) * 8;
    const _Float16* bt1 = BT1 + (size_t)(dug * 32) * 4096
                        + (size_t)(hi * 128 + wn * 32 + l5) * 8;

    f32x16 acc, accc;
#pragma unroll
    for (int r = 0; r < 16; r++) { acc[r] = 0.f; accc[r] = 0.f; }

    float4 fa;
    f16x8 B00, B01, B10, B11, N00, N01, N10, N11;

    // ---- prologue: stage tile 0 into buf0; B(0) to regs; prefetch fa(1) ----
    fa = *(const float4*)(aptr);
    {
        f16x4 h0, h1;
        h2pair s0 = split2(fa.x); h0[0] = s0.h0; h1[0] = s0.h1;
        h2pair s1 = split2(fa.y); h0[1] = s1.h0; h1[1] = s1.h1;
        h2pair s2 = split2(fa.z); h0[2] = s2.h0; h1[2] = s2.h1;
        h2pair s3 = split2(fa.w); h0[3] = s3.h0; h1[3] = s3.h1;
        *(f16x4*)&lds[awofs] = h0;
        *(f16x4*)&lds[4096 + awofs] = h1;
    }
    B00 = *(const f16x8*)(bt0);
    B01 = *(const f16x8*)(bt0 + 2048);
    B10 = *(const f16x8*)(bt1);
    B11 = *(const f16x8*)(bt1 + 2048);
    fa = *(const float4*)(aptr + 32);
    asm volatile("s_waitcnt lgkmcnt(0)" ::: "memory");
    __builtin_amdgcn_s_barrier();

// One K-step. BCxy = plane x, k-chunk y (current); Nxy = next (loaded here).
#define K1_STEP(KT, BC00, BC01, BC10, BC11, BN00, BN01, BN10, BN11)            \
    {                                                                          \
        const int kt_ = (KT);                                                  \
        const int cur = (kt_ & 1) * 8192;                                      \
        const int nxt = cur ^ 8192;                                            \
        if (kt_ < 31) {                                                        \
            const _Float16* b0_ = bt0 + (size_t)(kt_ + 1) * 4096;              \
            const _Float16* b1_ = bt1 + (size_t)(kt_ + 1) * 4096;              \
            BN00 = *(const f16x8*)(b0_);                                       \
            BN01 = *(const f16x8*)(b0_ + 2048);                                \
            BN10 = *(const f16x8*)(b1_);                                       \
            BN11 = *(const f16x8*)(b1_ + 2048);                                \
        }                                                                      \
        asm volatile("" ::: "memory");                                         \
        if (kt_ < 31) {                                                        \
            f16x4 h0_, h1_;                                                    \
            h2pair s0_ = split2(fa.x); h0_[0] = s0_.h0; h1_[0] = s0_.h1;       \
            h2pair s1_ = split2(fa.y); h0_[1] = s1_.h0; h1_[1] = s1_.h1;       \
            h2pair s2_ = split2(fa.z); h0_[2] = s2_.h0; h1_[2] = s2_.h1;       \
            h2pair s3_ = split2(fa.w); h0_[3] = s3_.h0; h1_[3] = s3_.h1;       \
            *(f16x4*)&lds[nxt + awofs] = h0_;                                  \
            *(f16x4*)&lds[nxt + 4096 + awofs] = h1_;                           \
            if (kt_ < 30)                                                      \
                fa = *(const float4*)(aptr + (kt_ + 2) * 32);                  \
        }                                                                      \
        asm volatile("" ::: "memory");                                         \
        f16x8 A00, A10, A01, A11;                                              \
        {                                                                      \
            const int ro0 = ((0 * 2 + hi) * 128 + wm * 32 + l5) * 8;           \
            const int ro1 = ((1 * 2 + hi) * 128 + wm * 32 + l5) * 8;           \
            A00 = *(const f16x8*)&lds[cur + ro0];                              \
            A10 = *(const f16x8*)&lds[cur + 4096 + ro0];                       \
            A01 = *(const f16x8*)&lds[cur + ro1];                              \
            A11 = *(const f16x8*)&lds[cur + 4096 + ro1];                       \
        }                                                                      \
        __builtin_amdgcn_s_setprio(1);                                         \
        acc  = __builtin_amdgcn_mfma_f32_32x32x16_f16(A00, BC00, acc, 0, 0, 0);\
        accc = __builtin_amdgcn_mfma_f32_32x32x16_f16(A00, BC10, accc, 0, 0, 0);\
        accc = __builtin_amdgcn_mfma_f32_32x32x16_f16(A10, BC00, accc, 0, 0, 0);\
        acc  = __builtin_amdgcn_mfma_f32_32x32x16_f16(A01, BC01, acc, 0, 0, 0);\
        accc = __builtin_amdgcn_mfma_f32_32x32x16_f16(A01, BC11, accc, 0, 0, 0);\
        accc = __builtin_amdgcn_mfma_f32_32x32x16_f16(A11, BC01, accc, 0, 0, 0);\
        __builtin_amdgcn_s_setprio(0);                                         \
        if (kt_ < 31) {                                                        \
            asm volatile("s_waitcnt lgkmcnt(0)" ::: "memory");                 \
            __builtin_amdgcn_s_barrier();                                      \
        }                                                                      \
    }

    for (int k2 = 0; k2 < 16; k2++) {
        K1_STEP(2 * k2,     B00, B01, B10, B11, N00, N01, N10, N11);
        K1_STEP(2 * k2 + 1, N00, N01, N10, N11, B00, B01, B10, B11);
    }
#undef K1_STEP

    // epilogue: h = relu(acc_total + bd[n]); g += Wp[n]*h reduced over n(=l5)
    const float bdv = bd[du0 + wn * 32 + l5];
    const float wpv = Wp[du0 + wn * 32 + l5];
    float out = 0.f;
#pragma unroll
    for (int r = 0; r < 16; r++) {
        float h = acc[r] + 4.8828125e-4f * accc[r] + bdv;
        h = h > 0.f ? h : 0.f;
        float s = wpv * h;
        s += __shfl_xor(s, 1);
        s += __shfl_xor(s, 2);
        s += __shfl_xor(s, 4);
        s += __shfl_xor(s, 8);
        s += __shfl_xor(s, 16);
        if (l5 == r) out = s;
    }
    if (l5 < 16) {
        const int row = wm * 32 + (l5 & 3) + 8 * (l5 >> 2) + 4 * hi;
        atomicAdd(&g[row0 + row], out);
    }
}

// ============================================================================
// k2: per-batch sigmoid + masked sum + scale + sequential scan.
// ============================================================================
__global__ __launch_bounds__(256) void k2_scan(
    const float* __restrict__ g, const int* __restrict__ in_len,
    const int* __restrict__ tgt_len, const float* __restrict__ bp,
    float* __restrict__ c_a, float* __restrict__ c_b,
    int* __restrict__ fire_t, int* __restrict__ n_fired,
    float* __restrict__ out_mask, float* __restrict__ out_dur,
    float* __restrict__ out_qty)
{
    __shared__ float w[TLEN];
    __shared__ float ca[TLEN];
    __shared__ float cb[TLEN];
    __shared__ int fires[MAXF];
    __shared__ float ssum[256];
    __shared__ float s_scale;
    __shared__ int s_nf;

    const int b = blockIdx.x;
    const int tid = threadIdx.x;
    const int len = in_len[b];
    const float bpv = bp[0];

    float local = 0.f;
    for (int t = tid; t < TLEN; t += 256) {
        float gv = g[b * TLEN + t] + bpv;
        float s = 1.f / (1.f + expf(-gv));
        float ow = (t < len) ? s : 0.f;
        w[t] = ow;
        local += ow;
    }
    ssum[tid] = local;
    __syncthreads();
    for (int st = 128; st > 0; st >>= 1) {
        if (tid < st) ssum[tid] += ssum[tid + st];
        __syncthreads();
    }
    if (tid == 0) {
        float org_sum = ssum[0];
        out_qty[b] = org_sum;
        s_scale = (float)tgt_len[b] / (org_sum + 1e-8f);
    }
    __syncthreads();
    float scale = s_scale;
    for (int t = tid; t < TLEN; t += 256) w[t] *= scale;
    __syncthreads();

    if (tid == 0) {
        float accw = 0.f;
        int k = 0;
        int t = 0;
        for (; t + 8 <= len; t += 8) {
            float4 wa = *(const float4*)&w[t];
            float4 wb4 = *(const float4*)&w[t + 4];
            float wv8[8] = {wa.x, wa.y, wa.z, wa.w, wb4.x, wb4.y, wb4.z, wb4.w};
#pragma unroll
            for (int u = 0; u < 8; u++) {
                float wt = wv8[u];
                float aw = accw + wt;
                bool f = (aw >= 1.0f);
                float rem = 1.0f - accw;          // exact reference order
                float fb = wt - rem;
                ca[t + u] = f ? rem : wt;
                cb[t + u] = f ? fb : 0.f;
                fires[k & (MAXF - 1)] = t + u;    // commits on fire
                k += f ? 1 : 0;
                accw = f ? fb : aw;
            }
        }
        for (; t < len; t++) {
            float wt = w[t];
            float aw = accw + wt;
            bool f = (aw >= 1.0f);
            float rem = 1.0f - accw;
            float fb = wt - rem;
            ca[t] = f ? rem : wt;
            cb[t] = f ? fb : 0.f;
            fires[k & (MAXF - 1)] = t;
            k += f ? 1 : 0;
            accw = f ? fb : aw;
        }
        s_nf = (k < MAXF) ? k : MAXF;
        n_fired[b] = s_nf;
    }
    __syncthreads();

    for (int t = tid; t < len; t += 256) {
        c_a[b * TLEN + t] = ca[t];
        c_b[b * TLEN + t] = cb[t];
    }
    const int nf = s_nf;
    for (int jj = tid; jj < nf; jj += 256) {
        int tj = fires[jj];
        fire_t[b * MAXF + jj] = tj;
        out_mask[b * TLEN + jj] = 1.0f;
        int prev = (jj == 0) ? 0 : fires[jj - 1];
        out_dur[b * TLEN + jj] = (float)(tj - prev);
    }
    if (tid == 0 && nf == 0) out_mask[b * TLEN] = 1.0f;
}

// ============================================================================
// k3a: compact fired frames (segmented weighted sums, ascending t), writing
// fp16 split planes row-major [b][frame][k]; rows >= n_fired zero-filled.
// ============================================================================
__global__ __launch_bounds__(256) void k3a_compact(
    const float* __restrict__ enc, const float* __restrict__ c_a,
    const float* __restrict__ c_b, const int* __restrict__ fire_t,
    const int* __restrict__ n_fired, _Float16* __restrict__ C0,
    _Float16* __restrict__ C1)
{
    const int b = blockIdx.y;
    const int k = blockIdx.x;
    const int tid = threadIdx.x;
    _Float16* d0 = C0 + ((size_t)b * MAXF + k) * CDIM + tid * 4;
    _Float16* d1 = C1 + ((size_t)b * MAXF + k) * CDIM + tid * 4;
    if (k >= n_fired[b]) {
        f16x4 z = {(_Float16)0.f, (_Float16)0.f, (_Float16)0.f, (_Float16)0.f};
        *(f16x4*)d0 = z;
        *(f16x4*)d1 = z;
        return;
    }
    const int tend = fire_t[b * MAXF + k];
    const int tprev = (k == 0) ? -1 : fire_t[b * MAXF + k - 1];
    float ax = 0.f, ay = 0.f, az = 0.f, aw = 0.f;
    const int tstart = (tprev < 0) ? 0 : tprev;
    for (int t = tstart; t <= tend; t++) {
        float coef = (t == tprev) ? c_b[b * TLEN + t] : c_a[b * TLEN + t];
        const float4 e = *(const float4*)(enc + ((size_t)b * TLEN + t) * CDIM + tid * 4);
        ax += coef * e.x;
        ay += coef * e.y;
        az += coef * e.z;
        aw += coef * e.w;
    }
    f16x4 h0, h1;
    h2pair s0 = split2(ax); h0[0] = s0.h0; h1[0] = s0.h1;
    h2pair s1 = split2(ay); h0[1] = s1.h0; h1[1] = s1.h1;
    h2pair s2 = split2(az); h0[2] = s2.h0; h1[2] = s2.h1;
    h2pair s3 = split2(aw); h0[3] = s3.h0; h1[3] = s3.h1;
    *(f16x4*)d0 = h0;
    *(f16x4*)d1 = h1;
}

// ============================================================================
// k3b: cif_outputs[b,j,o] = compact[b,j,:].Wo[o,:] — fp16-3 MFMA.
// ============================================================================
__global__ __launch_bounds__(256, 2) void k3b_outproj(
    const _Float16* __restrict__ C0, const _Float16* __restrict__ C1,
    const _Float16* __restrict__ W0, const _Float16* __restrict__ W1,
    const int* __restrict__ n_fired, float* __restrict__ out0)
{
    __shared__ __align__(16) _Float16 lds[16384];

    const int b = blockIdx.z;
    const int nf = n_fired[b];
    const int j0 = blockIdx.x * 128;
    if (j0 >= nf) return;
    const int o0 = blockIdx.y * 128;
    const int tid = threadIdx.x;
    const int lane = tid & 63;
    const int wv = tid >> 6;
    const int l5 = lane & 31;
    const int hi = lane >> 5;
    const int mtb = (wv & 1) * 64;
    const int ntb = (wv >> 1) * 64;

    const int sr = tid >> 1;
    const int sh = tid & 1;
    const _Float16* a0p = C0 + ((size_t)b * MAXF + j0 + sr) * CDIM + sh * 16;
    const _Float16* a1p = C1 + ((size_t)b * MAXF + j0 + sr) * CDIM + sh * 16;
    const _Float16* b0p = W0 + (size_t)(o0 + sr) * CDIM + sh * 16;
    const _Float16* b1p = W1 + (size_t)(o0 + sr) * CDIM + sh * 16;

    f32x16 acc[2][2], accc[2][2];
#pragma unroll
    for (int mt = 0; mt < 2; mt++)
#pragma unroll
        for (int nt = 0; nt < 2; nt++)
#pragma unroll
            for (int r = 0; r < 16; r++) { acc[mt][nt][r] = 0.f; accc[mt][nt][r] = 0.f; }

    f16x8 xa0[2], xa1[2], xb0[2], xb1[2];
#pragma unroll
    for (int c = 0; c < 2; c++) {
        xa0[c] = *(const f16x8*)(a0p + c * 8);
        xa1[c] = *(const f16x8*)(a1p + c * 8);
        xb0[c] = *(const f16x8*)(b0p + c * 8);
        xb1[c] = *(const f16x8*)(b1p + c * 8);
    }

    for (int kt = 0; kt < 32; ++kt) {
        __syncthreads();
#pragma unroll
        for (int c = 0; c < 2; c++) {
            *(f16x8*)&lds[((sh * 2 + c) * 128 + sr) * 8] = xa0[c];
            *(f16x8*)&lds[4096 + ((sh * 2 + c) * 128 + sr) * 8] = xa1[c];
            *(f16x8*)&lds[8192 + ((sh * 2 + c) * 128 + sr) * 8] = xb0[c];
            *(f16x8*)&lds[12288 + ((sh * 2 + c) * 128 + sr) * 8] = xb1[c];
        }
        __syncthreads();
        if (kt < 31) {
            const int o = (kt + 1) * 32;
#pragma unroll
            for (int c = 0; c < 2; c++) {
                xa0[c] = *(const f16x8*)(a0p + o + c * 8);
                xa1[c] = *(const f16x8*)(a1p + o + c * 8);
                xb0[c] = *(const f16x8*)(b0p + o + c * 8);
                xb1[c] = *(const f16x8*)(b1p + o + c * 8);
            }
        }
#pragma unroll
        for (int ks = 0; ks < 2; ks++) {
            const int ch = ks * 2 + hi;
            f16x8 A0[2], A1[2], B0[2], B1[2];
#pragma unroll
            for (int mt = 0; mt < 2; mt++) {
                const int row = mtb + mt * 32 + l5;
                A0[mt] = *(const f16x8*)&lds[(ch * 128 + row) * 8];
                A1[mt] = *(const f16x8*)&lds[4096 + (ch * 128 + row) * 8];
            }
#pragma unroll
            for (int nt = 0; nt < 2; nt++) {
                const int row = ntb + nt * 32 + l5;
                B0[nt] = *(const f16x8*)&lds[8192 + (ch * 128 + row) * 8];
                B1[nt] = *(const f16x8*)&lds[12288 + (ch * 128 + row) * 8];
            }
#pragma unroll
            for (int mt = 0; mt < 2; mt++)
#pragma unroll
                for (int nt = 0; nt < 2; nt++) {
                    acc[mt][nt] = __builtin_amdgcn_mfma_f32_32x32x16_f16(
                        A0[mt], B0[nt], acc[mt][nt], 0, 0, 0);
                    accc[mt][nt] = __builtin_amdgcn_mfma_f32_32x32x16_f16(
                        A0[mt], B1[nt], accc[mt][nt], 0, 0, 0);
                    accc[mt][nt] = __builtin_amdgcn_mfma_f32_32x32x16_f16(
                        A1[mt], B0[nt], accc[mt][nt], 0, 0, 0);
                }
        }
    }

#pragma unroll
    for (int mt = 0; mt < 2; mt++)
#pragma unroll
        for (int nt = 0; nt < 2; nt++)
#pragma unroll
            for (int r = 0; r < 16; r++) {
                float val = acc[mt][nt][r] + 4.8828125e-4f * accc[mt][nt][r];
                int m = mtb + mt * 32 + (r & 3) + 8 * (r >> 2) + 4 * hi;
                int col = o0 + ntb + nt * 32 + l5;
                out0[((size_t)b * TLEN + j0 + m) * OUTDIM + col] = val;
            }
}

// ============================================================================
// Host launch
// ============================================================================
extern "C" void kernel_launch(void* const* d_in, const int* in_sizes, int n_in,
                              void* d_out, int out_size, void* d_ws, size_t ws_size,
                              hipStream_t stream)
{
    const float* enc = (const float*)d_in[0];
    const int* in_len = (const int*)d_in[1];
    const int* tgt_len = (const int*)d_in[2];
    const float* Wd = (const float*)d_in[3];
    const float* bd = (const float*)d_in[4];
    const float* Wp = (const float*)d_in[5];
    const float* bp = (const float*)d_in[6];
    const float* Wo = (const float*)d_in[7];

    char* ws = (char*)d_ws;
    float* g       = (float*)(ws + 0);             // 128 KB
    float* c_a     = (float*)(ws + 131072);        // 128 KB
    float* c_b     = (float*)(ws + 262144);        // 128 KB
    int* fire_t    = (int*)(ws + 393216);          // 32 KB
    int* n_fired   = (int*)(ws + 425984);          // 64 B
    _Float16* WdT0 = (_Float16*)(ws + 458752);     // 2 MB tiled
    _Float16* WdT1 = (_Float16*)(ws + 2555904);    // 2 MB
    _Float16* Wo0  = (_Float16*)(ws + 4653056);    // 1 MB row-major
    _Float16* Wo1  = (_Float16*)(ws + 5701632);    // 1 MB
    _Float16* C0   = (_Float16*)(ws + 6750208);    // 16 MB
    _Float16* C1   = (_Float16*)(ws + 23527424);   // 16 MB  (end ~40.3 MB)

    float* out0 = (float*)d_out;
    float* out_mask = out0 + (size_t)BSZ * TLEN * OUTDIM;
    float* out_dur = out_mask + (size_t)BSZ * TLEN;
    float* out_qty = out_dur + (size_t)BSZ * TLEN;

    (void)hipMemsetAsync(g, 0, 131072, stream);
    (void)hipMemsetAsync(d_out, 0, (size_t)out_size * 4, stream);

    k0a_split_wd<<<dim3(8, 32), 128, 0, stream>>>(Wd, WdT0, WdT1);
    k0c_split_wo<<<512, 256, 0, stream>>>(Wo, Wo0, Wo1);
    k1_weight_gemm<<<2048, 1024, 0, stream>>>(enc, WdT0, WdT1, bd, Wp, g);
    k2_scan<<<BSZ, 256, 0, stream>>>(g, in_len, tgt_len, bp, c_a, c_b,
                                     fire_t, n_fired, out_mask, out_dur, out_qty);
    k3a_compact<<<dim3(MAXF, BSZ), 256, 0, stream>>>(enc, c_a, c_b, fire_t,
                                                     n_fired, C0, C1);
    k3b_outproj<<<dim3(4, 4, BSZ), 256, 0, stream>>>(C0, C1, Wo0, Wo1,
                                                     n_fired, out0);
}

// Round 6
// 583.574 us; speedup vs baseline: 1.2049x; 1.2049x over previous
//
#include <hip/hip_runtime.h>
#include <cstdint>
#include <cstddef>

#define BSZ 16
#define TLEN 2048
#define CDIM 1024
#define OUTDIM 512
#define MAXF 512

typedef _Float16 f16x8 __attribute__((ext_vector_type(8)));
typedef _Float16 f16x4 __attribute__((ext_vector_type(4)));
typedef float f32x16 __attribute__((ext_vector_type(16)));

__device__ __forceinline__ void gl_lds16(const void* g, void* l) {
    __builtin_amdgcn_global_load_lds(
        (const __attribute__((address_space(1))) void*)g,
        (__attribute__((address_space(3))) void*)l, 16, 0, 0);
}

// exact 2-term fp16 split: a = h0 + h1 * 2^-11  (h1 pre-scaled by 2^11)
struct h2pair { _Float16 h0, h1; };
__device__ __forceinline__ h2pair split2(float a) {
    h2pair o;
    o.h0 = (_Float16)a;
    float r = a - (float)o.h0;       // exact (Sterbenz)
    o.h1 = (_Float16)(r * 2048.0f);
    return o;
}

// ============================================================================
// k0a: split Wd into 2 fp16 planes in k1's TILED layout:
// plane[(dut*32+ktl)*4096 + (c*128 + r)*8 + j] = Wd[dut*128+r][ktl*32+c*8+j]
// ============================================================================
__global__ __launch_bounds__(128) void k0a_split_wd(
    const float* __restrict__ Wd, _Float16* __restrict__ B0,
    _Float16* __restrict__ B1)
{
    const int dut = blockIdx.x;     // 8
    const int ktl = blockIdx.y;     // 32
    const int r = threadIdx.x;      // 128
    const float* src = Wd + (size_t)(dut * 128 + r) * CDIM + ktl * 32;
    float v[32];
#pragma unroll
    for (int j = 0; j < 8; j++) *(float4*)&v[j * 4] = *(const float4*)(src + j * 4);
    const size_t tb = (size_t)(dut * 32 + ktl) * 4096;
#pragma unroll
    for (int c = 0; c < 4; c++) {
        f16x8 h0, h1;
#pragma unroll
        for (int j = 0; j < 8; j++) {
            h2pair s = split2(v[c * 8 + j]);
            h0[j] = s.h0;
            h1[j] = s.h1;
        }
        *(f16x8*)&B0[tb + (c * 128 + r) * 8] = h0;
        *(f16x8*)&B1[tb + (c * 128 + r) * 8] = h1;
    }
}

// ============================================================================
// k0c: split Wo into 2 fp16 planes, row-major [o][k]
// ============================================================================
__global__ __launch_bounds__(256) void k0c_split_wo(
    const float* __restrict__ Wo, _Float16* __restrict__ W0,
    _Float16* __restrict__ W1)
{
    const int i = (blockIdx.x * 256 + threadIdx.x) * 4;
    float4 v = *(const float4*)(Wo + i);
    f16x4 h0, h1;
    h2pair s0 = split2(v.x); h0[0] = s0.h0; h1[0] = s0.h1;
    h2pair s1 = split2(v.y); h0[1] = s1.h0; h1[1] = s1.h1;
    h2pair s2 = split2(v.z); h0[2] = s2.h0; h1[2] = s2.h1;
    h2pair s3 = split2(v.w); h0[3] = s3.h0; h1[3] = s3.h1;
    *(f16x4*)&W0[i] = h0;
    *(f16x4*)&W1[i] = h1;
}

// ============================================================================
// k1: g[row] = sum_du Wp[du]*relu(enc[row,:].Wd[du,:] + bd[du])
// R4's proven kernel, verbatim (263.6 us, MfmaUtil 36, occ 42%). Two-acc
// fp16-3 scheme is bit-exactness-locked (fire-flip risk analysis); this
// structure is its constrained optimum across 6 measured variants.
// ============================================================================
__global__ __launch_bounds__(512, 4) void k1_weight_gemm(
    const float* __restrict__ enc, const _Float16* __restrict__ BT0,
    const _Float16* __restrict__ BT1, const float* __restrict__ bd,
    const float* __restrict__ Wp, float* __restrict__ g)
{
    // 2 buffers x (A0|A1|B0|B1 regions of 4096 halves) = 32768 halves = 64KB
    __shared__ __align__(16) _Float16 lds[32768];

    const int tid = threadIdx.x;
    const int lane = tid & 63;
    const int wv = tid >> 6;        // 0..7
    const int l5 = lane & 31;
    const int hi = lane >> 5;
    const int mtb = (wv & 1) * 64;  // M half
    const int ntb = (wv >> 1) * 32; // N quarter (32 du)

    // XCD-aware decode: xcd = bx%8; each xcd handles 32 row-groups x 8 du
    const int bx = blockIdx.x;
    const int xcd = bx & 7;
    const int j = bx >> 3;
    const int rg = xcd * 32 + (j >> 3);
    const int dug = j & 7;
    const long row0 = (long)rg * 128;
    const int du0 = dug * 128;

    // A staging: row sr = (wv>>2)*64 + lane, k-octet sq = wv&3 (wave-uniform)
    const int sgrp = wv >> 2;       // 0..1
    const int sq = wv & 3;          // 0..3
    const int sr = sgrp * 64 + lane;
    const float* aptr = enc + (row0 + sr) * (long)CDIM + sq * 8;
    const int aw0 = (sq * 128 + sr) * 8;   // A0 LDS write offset (halves)

    // B staging: wave stages quarter sq of plane sgrp (2 x gl_lds16 of 1KB)
    const _Float16* bsrc = (sgrp ? BT1 : BT0)
        + (size_t)(dug * 32) * 4096 + sq * 1024 + lane * 8;
    const int bldofs = 8192 + sgrp * 4096 + sq * 1024;

    f32x16 acc[2], accc[2];
#pragma unroll
    for (int mt = 0; mt < 2; mt++)
#pragma unroll
        for (int r = 0; r < 16; r++) { acc[mt][r] = 0.f; accc[mt][r] = 0.f; }

    float fa[8];

    // ---- prologue: stage tile 0 into buf0, prefetch fa(tile 1) ----
    *(float4*)&fa[0] = *(const float4*)(aptr + 0);
    *(float4*)&fa[4] = *(const float4*)(aptr + 4);
    gl_lds16(bsrc, &lds[bldofs]);
    gl_lds16(bsrc + 512, &lds[bldofs + 512]);
    asm volatile("" ::: "memory");
    {
        f16x8 h0, h1;
#pragma unroll
        for (int jj = 0; jj < 8; jj++) {
            h2pair s = split2(fa[jj]);
            h0[jj] = s.h0;
            h1[jj] = s.h1;
        }
        *(f16x8*)&lds[aw0] = h0;
        *(f16x8*)&lds[4096 + aw0] = h1;
    }
    *(float4*)&fa[0] = *(const float4*)(aptr + 32);
    *(float4*)&fa[4] = *(const float4*)(aptr + 36);
    asm volatile("s_waitcnt vmcnt(2) lgkmcnt(0)" ::: "memory");
    __builtin_amdgcn_s_barrier();

    for (int kt = 0; kt < 32; ++kt) {
        const int cur = (kt & 1) * 16384;
        const int nxt = cur ^ 16384;
        __builtin_amdgcn_sched_barrier(0);

        if (kt < 31) {
            // B(kt+1) DMA into nxt — in flight through this tile's MFMA
            const _Float16* bs = bsrc + (size_t)(kt + 1) * 4096;
            gl_lds16(bs, &lds[nxt + bldofs]);
            gl_lds16(bs + 512, &lds[nxt + bldofs + 512]);
            asm volatile("" ::: "memory");
            // split fa (= tile kt+1) into nxt A planes
            f16x8 h0, h1;
#pragma unroll
            for (int jj = 0; jj < 8; jj++) {
                h2pair s = split2(fa[jj]);
                h0[jj] = s.h0;
                h1[jj] = s.h1;
            }
            *(f16x8*)&lds[nxt + aw0] = h0;
            *(f16x8*)&lds[nxt + 4096 + aw0] = h1;
            if (kt < 30) {
                *(float4*)&fa[0] = *(const float4*)(aptr + (kt + 2) * 32);
                *(float4*)&fa[4] = *(const float4*)(aptr + (kt + 2) * 32 + 4);
            }
            asm volatile("" ::: "memory");
        }

        // ---- compute on cur: 2 phases (cq = p*2 + hi), 6 MFMA each ----
#pragma unroll
        for (int p = 0; p < 2; p++) {
            const int cq = p * 2 + hi;
            f16x8 A0[2], A1[2], B0, B1;
#pragma unroll
            for (int mt = 0; mt < 2; mt++) {
                const int ro = (cq * 128 + mtb + mt * 32 + l5) * 8;
                A0[mt] = *(const f16x8*)&lds[cur + ro];
                A1[mt] = *(const f16x8*)&lds[cur + 4096 + ro];
            }
            {
                const int ro = (cq * 128 + ntb + l5) * 8;
                B0 = *(const f16x8*)&lds[cur + 8192 + ro];
                B1 = *(const f16x8*)&lds[cur + 12288 + ro];
            }
            __builtin_amdgcn_s_setprio(1);
#pragma unroll
            for (int mt = 0; mt < 2; mt++) {
                acc[mt] = __builtin_amdgcn_mfma_f32_32x32x16_f16(
                    A0[mt], B0, acc[mt], 0, 0, 0);
                accc[mt] = __builtin_amdgcn_mfma_f32_32x32x16_f16(
                    A0[mt], B1, accc[mt], 0, 0, 0);
                accc[mt] = __builtin_amdgcn_mfma_f32_32x32x16_f16(
                    A1[mt], B0, accc[mt], 0, 0, 0);
            }
            __builtin_amdgcn_s_setprio(0);
        }

        // counted drain: B DMAs complete; fa prefetch stays in flight
        if (kt < 31) {
            if (kt < 30)
                asm volatile("s_waitcnt vmcnt(2) lgkmcnt(0)" ::: "memory");
            else
                asm volatile("s_waitcnt vmcnt(0) lgkmcnt(0)" ::: "memory");
            __builtin_amdgcn_s_barrier();
        }
    }

    // epilogue: h = relu(acc_total + bd[n]); g += Wp[n]*h reduced over n
    const float bdv = bd[du0 + ntb + l5];
    const float wpv = Wp[du0 + ntb + l5];
    float out = 0.f;
#pragma unroll
    for (int mt = 0; mt < 2; mt++)
#pragma unroll
        for (int r = 0; r < 16; r++) {
            float h = acc[mt][r] + 4.8828125e-4f * accc[mt][r] + bdv;
            h = h > 0.f ? h : 0.f;
            float s = wpv * h;
            s += __shfl_xor(s, 1);
            s += __shfl_xor(s, 2);
            s += __shfl_xor(s, 4);
            s += __shfl_xor(s, 8);
            s += __shfl_xor(s, 16);
            if (l5 == mt * 16 + r) out = s;
        }
    const int mt_sel = l5 >> 4;
    const int r_sel = l5 & 15;
    const int row = mtb + mt_sel * 32 + (r_sel & 3) + 8 * (r_sel >> 2) + 4 * hi;
    atomicAdd(&g[row0 + row], out);
}

// ============================================================================
// k2: per-batch sigmoid + masked sum + scale + sequential scan.
// ============================================================================
__global__ __launch_bounds__(256) void k2_scan(
    const float* __restrict__ g, const int* __restrict__ in_len,
    const int* __restrict__ tgt_len, const float* __restrict__ bp,
    float* __restrict__ c_a, float* __restrict__ c_b,
    int* __restrict__ fire_t, int* __restrict__ n_fired,
    float* __restrict__ out_mask, float* __restrict__ out_dur,
    float* __restrict__ out_qty)
{
    __shared__ float w[TLEN];
    __shared__ float ca[TLEN];
    __shared__ float cb[TLEN];
    __shared__ int fires[MAXF];
    __shared__ float ssum[256];
    __shared__ float s_scale;
    __shared__ int s_nf;

    const int b = blockIdx.x;
    const int tid = threadIdx.x;
    const int len = in_len[b];
    const float bpv = bp[0];

    float local = 0.f;
    for (int t = tid; t < TLEN; t += 256) {
        float gv = g[b * TLEN + t] + bpv;
        float s = 1.f / (1.f + expf(-gv));
        float ow = (t < len) ? s : 0.f;
        w[t] = ow;
        local += ow;
    }
    ssum[tid] = local;
    __syncthreads();
    for (int st = 128; st > 0; st >>= 1) {
        if (tid < st) ssum[tid] += ssum[tid + st];
        __syncthreads();
    }
    if (tid == 0) {
        float org_sum = ssum[0];
        out_qty[b] = org_sum;
        s_scale = (float)tgt_len[b] / (org_sum + 1e-8f);
    }
    __syncthreads();
    float scale = s_scale;
    for (int t = tid; t < TLEN; t += 256) w[t] *= scale;
    __syncthreads();

    if (tid == 0) {
        float accw = 0.f;
        int k = 0;
        int t = 0;
        for (; t + 8 <= len; t += 8) {
            float4 wa = *(const float4*)&w[t];
            float4 wb4 = *(const float4*)&w[t + 4];
            float wv8[8] = {wa.x, wa.y, wa.z, wa.w, wb4.x, wb4.y, wb4.z, wb4.w};
#pragma unroll
            for (int u = 0; u < 8; u++) {
                float wt = wv8[u];
                float aw = accw + wt;
                bool f = (aw >= 1.0f);
                float rem = 1.0f - accw;          // exact reference order
                float fb = wt - rem;
                ca[t + u] = f ? rem : wt;
                cb[t + u] = f ? fb : 0.f;
                fires[k & (MAXF - 1)] = t + u;    // commits on fire
                k += f ? 1 : 0;
                accw = f ? fb : aw;
            }
        }
        for (; t < len; t++) {
            float wt = w[t];
            float aw = accw + wt;
            bool f = (aw >= 1.0f);
            float rem = 1.0f - accw;
            float fb = wt - rem;
            ca[t] = f ? rem : wt;
            cb[t] = f ? fb : 0.f;
            fires[k & (MAXF - 1)] = t;
            k += f ? 1 : 0;
            accw = f ? fb : aw;
        }
        s_nf = (k < MAXF) ? k : MAXF;
        n_fired[b] = s_nf;
    }
    __syncthreads();

    for (int t = tid; t < len; t += 256) {
        c_a[b * TLEN + t] = ca[t];
        c_b[b * TLEN + t] = cb[t];
    }
    const int nf = s_nf;
    for (int jj = tid; jj < nf; jj += 256) {
        int tj = fires[jj];
        fire_t[b * MAXF + jj] = tj;
        out_mask[b * TLEN + jj] = 1.0f;
        int prev = (jj == 0) ? 0 : fires[jj - 1];
        out_dur[b * TLEN + jj] = (float)(tj - prev);
    }
    if (tid == 0 && nf == 0) out_mask[b * TLEN] = 1.0f;
}

// ============================================================================
// k3a: compact fired frames (segmented weighted sums, ascending t), writing
// fp16 split planes row-major [b][frame][k]; rows >= n_fired zero-filled.
// ============================================================================
__global__ __launch_bounds__(256) void k3a_compact(
    const float* __restrict__ enc, const float* __restrict__ c_a,
    const float* __restrict__ c_b, const int* __restrict__ fire_t,
    const int* __restrict__ n_fired, _Float16* __restrict__ C0,
    _Float16* __restrict__ C1)
{
    const int b = blockIdx.y;
    const int k = blockIdx.x;
    const int tid = threadIdx.x;
    _Float16* d0 = C0 + ((size_t)b * MAXF + k) * CDIM + tid * 4;
    _Float16* d1 = C1 + ((size_t)b * MAXF + k) * CDIM + tid * 4;
    if (k >= n_fired[b]) {
        f16x4 z = {(_Float16)0.f, (_Float16)0.f, (_Float16)0.f, (_Float16)0.f};
        *(f16x4*)d0 = z;
        *(f16x4*)d1 = z;
        return;
    }
    const int tend = fire_t[b * MAXF + k];
    const int tprev = (k == 0) ? -1 : fire_t[b * MAXF + k - 1];
    float ax = 0.f, ay = 0.f, az = 0.f, aw = 0.f;
    const int tstart = (tprev < 0) ? 0 : tprev;
    for (int t = tstart; t <= tend; t++) {
        float coef = (t == tprev) ? c_b[b * TLEN + t] : c_a[b * TLEN + t];
        const float4 e = *(const float4*)(enc + ((size_t)b * TLEN + t) * CDIM + tid * 4);
        ax += coef * e.x;
        ay += coef * e.y;
        az += coef * e.z;
        aw += coef * e.w;
    }
    f16x4 h0, h1;
    h2pair s0 = split2(ax); h0[0] = s0.h0; h1[0] = s0.h1;
    h2pair s1 = split2(ay); h0[1] = s1.h0; h1[1] = s1.h1;
    h2pair s2 = split2(az); h0[2] = s2.h0; h1[2] = s2.h1;
    h2pair s3 = split2(aw); h0[3] = s3.h0; h1[3] = s3.h1;
    *(f16x4*)d0 = h0;
    *(f16x4*)d1 = h1;
}

// ============================================================================
// k3b: cif_outputs[b,j,o] = compact[b,j,:].Wo[o,:] — fp16-3 MFMA.
// REDESIGN: BM=64 (was 128), grid (8,4,16)=512 blocks for ~2x machine fill
// at nf~350, and wave tile 64x32 (was 64x64) -> acc 64 AGPR (was 256, which
// was spilling/1-wave-per-SIMD). 256 thr = 4 waves (1M x 4N). LDS 24 KB.
// Per-output 3-MFMA sequence and kt/ks order bit-identical to before.
// ============================================================================
__global__ __launch_bounds__(256) void k3b_outproj(
    const _Float16* __restrict__ C0, const _Float16* __restrict__ C1,
    const _Float16* __restrict__ W0, const _Float16* __restrict__ W1,
    const int* __restrict__ n_fired, float* __restrict__ out0)
{
    // A0[0,2048) A1[2048,4096) B0[4096,8192) B1[8192,12288) halves = 24 KB
    __shared__ __align__(16) _Float16 lds[12288];

    const int b = blockIdx.z;
    const int nf = n_fired[b];
    const int j0 = blockIdx.x * 64;
    if (j0 >= nf) return;
    const int o0 = blockIdx.y * 128;
    const int tid = threadIdx.x;
    const int lane = tid & 63;
    const int wv = tid >> 6;        // 0..3
    const int l5 = lane & 31;
    const int hi = lane >> 5;
    const int ntb = wv * 32;        // N quarter

    // B staging: 128 rows, 2 k-halves, 2 chunks (as before)
    const int sr = tid >> 1;
    const int sh = tid & 1;
    const _Float16* b0p = W0 + (size_t)(o0 + sr) * CDIM + sh * 16;
    const _Float16* b1p = W1 + (size_t)(o0 + sr) * CDIM + sh * 16;
    // A staging: 64 rows, 4 k-octets, 1 f16x8 per plane per thread
    const int ar = tid >> 2;
    const int aq = tid & 3;
    const _Float16* a0p = C0 + ((size_t)b * MAXF + j0 + ar) * CDIM + aq * 8;
    const _Float16* a1p = C1 + ((size_t)b * MAXF + j0 + ar) * CDIM + aq * 8;
    const int awofs = (aq * 64 + ar) * 8;

    f32x16 acc[2], accc[2];
#pragma unroll
    for (int mt = 0; mt < 2; mt++)
#pragma unroll
        for (int r = 0; r < 16; r++) { acc[mt][r] = 0.f; accc[mt][r] = 0.f; }

    f16x8 xa0, xa1, xb0[2], xb1[2];
    xa0 = *(const f16x8*)(a0p);
    xa1 = *(const f16x8*)(a1p);
#pragma unroll
    for (int c = 0; c < 2; c++) {
        xb0[c] = *(const f16x8*)(b0p + c * 8);
        xb1[c] = *(const f16x8*)(b1p + c * 8);
    }

    for (int kt = 0; kt < 32; ++kt) {
        __syncthreads();
        *(f16x8*)&lds[awofs] = xa0;
        *(f16x8*)&lds[2048 + awofs] = xa1;
#pragma unroll
        for (int c = 0; c < 2; c++) {
            *(f16x8*)&lds[4096 + ((sh * 2 + c) * 128 + sr) * 8] = xb0[c];
            *(f16x8*)&lds[8192 + ((sh * 2 + c) * 128 + sr) * 8] = xb1[c];
        }
        __syncthreads();
        if (kt < 31) {
            const int o = (kt + 1) * 32;
            xa0 = *(const f16x8*)(a0p + o);
            xa1 = *(const f16x8*)(a1p + o);
#pragma unroll
            for (int c = 0; c < 2; c++) {
                xb0[c] = *(const f16x8*)(b0p + o + c * 8);
                xb1[c] = *(const f16x8*)(b1p + o + c * 8);
            }
        }
#pragma unroll
        for (int ks = 0; ks < 2; ks++) {
            const int ch = ks * 2 + hi;
            f16x8 A0[2], A1[2], B0, B1;
#pragma unroll
            for (int mt = 0; mt < 2; mt++) {
                const int ro = (ch * 64 + mt * 32 + l5) * 8;
                A0[mt] = *(const f16x8*)&lds[ro];
                A1[mt] = *(const f16x8*)&lds[2048 + ro];
            }
            {
                const int ro = (ch * 128 + ntb + l5) * 8;
                B0 = *(const f16x8*)&lds[4096 + ro];
                B1 = *(const f16x8*)&lds[8192 + ro];
            }
#pragma unroll
            for (int mt = 0; mt < 2; mt++) {
                acc[mt] = __builtin_amdgcn_mfma_f32_32x32x16_f16(
                    A0[mt], B0, acc[mt], 0, 0, 0);
                accc[mt] = __builtin_amdgcn_mfma_f32_32x32x16_f16(
                    A0[mt], B1, accc[mt], 0, 0, 0);
                accc[mt] = __builtin_amdgcn_mfma_f32_32x32x16_f16(
                    A1[mt], B0, accc[mt], 0, 0, 0);
            }
        }
    }

#pragma unroll
    for (int mt = 0; mt < 2; mt++)
#pragma unroll
        for (int r = 0; r < 16; r++) {
            float val = acc[mt][r] + 4.8828125e-4f * accc[mt][r];
            int m = mt * 32 + (r & 3) + 8 * (r >> 2) + 4 * hi;
            int col = o0 + ntb + l5;
            out0[((size_t)b * TLEN + j0 + m) * OUTDIM + col] = val;
        }
}

// ============================================================================
// Host launch
// ============================================================================
extern "C" void kernel_launch(void* const* d_in, const int* in_sizes, int n_in,
                              void* d_out, int out_size, void* d_ws, size_t ws_size,
                              hipStream_t stream)
{
    const float* enc = (const float*)d_in[0];
    const int* in_len = (const int*)d_in[1];
    const int* tgt_len = (const int*)d_in[2];
    const float* Wd = (const float*)d_in[3];
    const float* bd = (const float*)d_in[4];
    const float* Wp = (const float*)d_in[5];
    const float* bp = (const float*)d_in[6];
    const float* Wo = (const float*)d_in[7];

    char* ws = (char*)d_ws;
    float* g       = (float*)(ws + 0);             // 128 KB
    float* c_a     = (float*)(ws + 131072);        // 128 KB
    float* c_b     = (float*)(ws + 262144);        // 128 KB
    int* fire_t    = (int*)(ws + 393216);          // 32 KB
    int* n_fired   = (int*)(ws + 425984);          // 64 B
    _Float16* WdT0 = (_Float16*)(ws + 458752);     // 2 MB tiled
    _Float16* WdT1 = (_Float16*)(ws + 2555904);    // 2 MB
    _Float16* Wo0  = (_Float16*)(ws + 4653056);    // 1 MB row-major
    _Float16* Wo1  = (_Float16*)(ws + 5701632);    // 1 MB
    _Float16* C0   = (_Float16*)(ws + 6750208);    // 16 MB
    _Float16* C1   = (_Float16*)(ws + 23527424);   // 16 MB  (end ~40.3 MB)

    float* out0 = (float*)d_out;
    float* out_mask = out0 + (size_t)BSZ * TLEN * OUTDIM;
    float* out_dur = out_mask + (size_t)BSZ * TLEN;
    float* out_qty = out_dur + (size_t)BSZ * TLEN;

    (void)hipMemsetAsync(g, 0, 131072, stream);
    (void)hipMemsetAsync(d_out, 0, (size_t)out_size * 4, stream);

    k0a_split_wd<<<dim3(8, 32), 128, 0, stream>>>(Wd, WdT0, WdT1);
    k0c_split_wo<<<512, 256, 0, stream>>>(Wo, Wo0, Wo1);
    k1_weight_gemm<<<2048, 512, 0, stream>>>(enc, WdT0, WdT1, bd, Wp, g);
    k2_scan<<<BSZ, 256, 0, stream>>>(g, in_len, tgt_len, bp, c_a, c_b,
                                     fire_t, n_fired, out_mask, out_dur, out_qty);
    k3a_compact<<<dim3(MAXF, BSZ), 256, 0, stream>>>(enc, c_a, c_b, fire_t,
                                                     n_fired, C0, C1);
    k3b_outproj<<<dim3(8, 4, BSZ), 256, 0, stream>>>(C0, C1, Wo0, Wo1,
                                                     n_fired, out0);
}